// Round 1
// baseline (356.236 us; speedup 1.0000x reference)
//
#include <hip/hip_runtime.h>
#include <stdint.h>

// Net_49177375539428: recursive tree-NN scorer, all-fp32.
//   k_base : base[n,:] = vecs[data[n]] @ Wd + bd ; d_score at n==pos.
//            4-way split accumulators to break the 300-FMA dependent chain.
//   k_tree : LEVEL-PARALLEL rewrite. 1024 thr (16 waves) per graph.
//            Setup: children lists (ascending, deterministic), depth via
//            pointer jumping (7 steps), bucket nodes by depth.
//            Rounds d=maxD..0: each wave owns one ready node: gather
//            base + child contribs from LDS, relu/pos/path handling,
//            stage emb row in LDS, wave-GEMV (2 cols/lane, all-d,
//            coalesced float2 W loads). Rounds ~= tree height (~15) vs
//            the old 128 serialized steps. Floor is the per-CU L1 port
//            (~122 nodes x 64KB W / ~153 GB/s ~= 51 us per graph/CU).
//   k_chain: unchanged from previous round (256 blocks, 4 e's per block).

#define NND 128
#define DD  128
#define GG  8
#define VD  300
#define CH  4          // e's per k_chain block

typedef unsigned int u32;

#define F_POS  (1<<16)
#define F_PATH (1<<17)

// ---------------- K1: base embeddings + d_score ----------------
__global__ void __launch_bounds__(128) k_base(
        const int* __restrict__ data, const int* __restrict__ posArr,
        const float* __restrict__ vecs, const float* __restrict__ dw,
        const float* __restrict__ db,   const float* __restrict__ sdw,
        const float* __restrict__ sb,
        float* __restrict__ base, float* __restrict__ dscore)
{
    __shared__ __align__(16) float row[VD];
    __shared__ float red[DD];
    int n = blockIdx.x, t = threadIdx.x;
    int id = data[n];
    const float4* vp = (const float4*)(vecs + (size_t)id * VD);  // 1200B rows
    for (int i = t; i < VD/4; i += 128) ((float4*)row)[i] = vp[i];
    __syncthreads();
    // 4 partial accumulators: dependent-chain 300 -> 75 FMAs each
    float a0 = db[t], a1 = 0.f, a2 = 0.f, a3 = 0.f;
    for (int d = 0; d < VD; d += 4){
        a0 = fmaf(row[d+0], dw[(d+0)*DD + t], a0);
        a1 = fmaf(row[d+1], dw[(d+1)*DD + t], a1);
        a2 = fmaf(row[d+2], dw[(d+2)*DD + t], a2);
        a3 = fmaf(row[d+3], dw[(d+3)*DD + t], a3);
    }
    float acc = (a0 + a1) + (a2 + a3);
    base[n*DD + t] = acc;
    if (n == posArr[0]){
        red[t] = acc * sdw[t];
        __syncthreads();
        for (int o = 64; o > 0; o >>= 1){ if (t < o) red[t] += red[t+o]; __syncthreads(); }
        if (t == 0) dscore[0] = sb[0] + red[0];
    }
}

// ---------------- K2: level-parallel tree sweep ----------------
// One block per graph, 1024 threads = 16 waves. Rounds = tree height.
// contrib[c] holds node c's finished contribution (W[e_c]^T emb_c + b).
// A node's own contrib row doubles as the emb staging buffer for its GEMV
// (wave-private during its round; LDS ops from one wave are in-order).
__global__ void __launch_bounds__(1024, 1) k_tree(
        const int* __restrict__ graphs, const int* __restrict__ edges,
        const int* __restrict__ posArr, const float* __restrict__ EW,
        const float* __restrict__ EB,   const float* __restrict__ base,
        float* __restrict__ vposG, float* __restrict__ uG, int* __restrict__ meta)
{
    __shared__ __align__(16) float contrib[NND-1][DD];   // 63.5 KB, nodes 0..126
    __shared__ int par_s[NND], eid_s[NND], flg_s[NND];
    __shared__ int ccnt[NND], cstart[NND], cidx[NND];
    __shared__ int dep[NND], anc[NND], lcnt[NND], lstart[NND], order[NND];
    __shared__ int maxD_s;

    int g = blockIdx.x, t = threadIdx.x;

    // ---- phase 1: load graph structure ----
    if (t < NND){
        par_s[t] = (t < NND-1) ? (t + graphs[g*NND + t]) : (NND-1);  // root self-parent
        eid_s[t] = edges[t];
        flg_s[t] = 0;
        ccnt[t]  = 0;
        lcnt[t]  = 0;
    }
    if (t == 0) maxD_s = 0;
    __syncthreads();

    // ---- phase 2: child counts, sibling slots, depth init, path walk ----
    int mySlot = 0;
    if (t < NND-1){
        int p = par_s[t];
        atomicAdd(&ccnt[p], 1);
        for (int c = 0; c < t; ++c) mySlot += (par_s[c] == p);  // ascending sibling order
    }
    if (t < NND){
        dep[t] = (t < NND-1) ? 1 : 0;
        anc[t] = par_s[t];                          // root: self (absorbing, dep contrib 0)
    }
    if (t == 0){
        int p = posArr[0];
        flg_s[p] |= F_POS;
        int c = par_s[p], s = 0;
        for (;;){
            flg_s[c] |= F_PATH | (s << 24);
            meta[g*(NND+1) + 1 + s] = c;
            ++s;
            if (c == NND-1) break;
            c = par_s[c];
        }
        meta[g*(NND+1)] = s;                        // path length L
    }
    __syncthreads();

    // ---- phase 3: child list offsets (exclusive sum of ccnt) ----
    if (t < NND){
        int s = 0;
        for (int p = 0; p < t; ++p) s += ccnt[p];
        cstart[t] = s;
    }
    __syncthreads();
    if (t < NND-1) cidx[cstart[par_s[t]] + mySlot] = t;

    // ---- phase 4: depth from root via pointer jumping (depth <= 127 < 2^7) ----
    for (int k = 0; k < 7; ++k){
        int d2 = 0, a2 = 0;
        if (t < NND){ d2 = dep[t] + dep[anc[t]]; a2 = anc[anc[t]]; }
        __syncthreads();
        if (t < NND){ dep[t] = d2; anc[t] = a2; }
        __syncthreads();
    }
    if (t < NND) atomicMax(&maxD_s, dep[t]);
    if (t < NND) atomicAdd(&lcnt[dep[t]], 1);
    __syncthreads();

    // ---- phase 5: bucket nodes by depth (deterministic ascending) ----
    if (t < NND){
        int s = 0;
        for (int d2 = 0; d2 < t; ++d2) s += lcnt[d2];   // lstart[depth]
        lstart[t] = s;
    }
    __syncthreads();
    if (t < NND){
        int d2 = dep[t], s = 0;
        for (int c = 0; c < t; ++c) s += (dep[c] == d2);
        order[lstart[d2] + s] = t;
    }
    __syncthreads();

    // ---- main: rounds from deepest depth up to root ----
    int w = t >> 6, l = t & 63;
    int c0 = 2*l;                                   // this lane's 2 output columns
    int maxD = maxD_s;

    for (int d = maxD; d >= 0; --d){
        int lo = lstart[d], cnt = lcnt[d];
        for (int q = w; q < cnt; q += 16){
            int n = order[lo + q];                  // wave-uniform
            // gather: base + sum of non-path child contribs (ascending order)
            float2 bse = *(const float2*)&base[n*DD + c0];
            float e0 = bse.x, e1 = bse.y;
            int cs = cstart[n], cc = ccnt[n];
            for (int j = 0; j < cc; ++j){
                int c = cidx[cs + j];
                if (!(flg_s[c] & (F_POS | F_PATH))){
                    float2 cv = *(const float2*)&contrib[c][c0];
                    e0 += cv.x; e1 += cv.y;
                }
            }
            int f = flg_s[n];
            if (f & F_POS){
                if (cc){ e0 = fmaxf(e0, 0.f); e1 = fmaxf(e1, 0.f); }   // post-relu if internal
                *(float2*)&vposG[g*DD + c0] = make_float2(e0, e1);
            } else if (f & F_PATH){
                int slot = ((u32)f) >> 24;
                *(float2*)&uG[((size_t)g*NND + slot)*DD + c0] = make_float2(e0, e1);  // PRE-relu
            } else {
                if (cc){ e0 = fmaxf(e0, 0.f); e1 = fmaxf(e1, 0.f); }
                // stage emb row in this node's own contrib slot
                *(float2*)&contrib[n][c0] = make_float2(e0, e1);
                asm volatile("s_waitcnt lgkmcnt(0)" ::: "memory");     // wave-internal LDS RAW
                int e = eid_s[n];
                const float* Wp = EW + (size_t)e*(DD*DD) + c0;
                float s0a=0.f, s1a=0.f, s0b=0.f, s1b=0.f;
                #pragma unroll 8
                for (int dd = 0; dd < DD/2; ++dd){
                    float x0 = contrib[n][dd];                          // LDS broadcast
                    float x1 = contrib[n][DD/2 + dd];
                    float2 w0 = *(const float2*)&Wp[(size_t)dd*DD];     // 512B/wave coalesced
                    float2 w1 = *(const float2*)&Wp[(size_t)(DD/2+dd)*DD];
                    s0a = fmaf(x0, w0.x, s0a); s1a = fmaf(x0, w0.y, s1a);
                    s0b = fmaf(x1, w1.x, s0b); s1b = fmaf(x1, w1.y, s1b);
                }
                float2 bb = *(const float2*)&EB[(size_t)e*DD + c0];
                // overwrite staged emb with the finished contribution
                *(float2*)&contrib[n][c0] = make_float2(s0a + s0b + bb.x,
                                                        s1a + s1b + bb.y);
            }
        }
        __syncthreads();
    }
}

// ---------------- K3: path chains, 4 edge-types per block ----------------
__global__ void __launch_bounds__(256, 1) k_chain(
        const int* __restrict__ edges,
        const float* __restrict__ EW, const float* __restrict__ EB,
        const float* __restrict__ SEW,
        const float* __restrict__ vposG, const float* __restrict__ uG,
        const int* __restrict__ meta, const float* __restrict__ dscore,
        float* __restrict__ outp)
{
    __shared__ __align__(16) float Vbuf[2][CH][DD];
    __shared__ float red[CH][4];
    int g = blockIdx.x >> 5, chunk = blockIdx.x & 31;
    int t = threadIdx.x, l = t & 63, w = t >> 6;
    int k4 = w*8 + (l & 7);
    int d0 = (l >> 3) * 16;
    bool owner = ((l >> 3) == 0);
    int eBase = chunk * CH;
    int L = meta[g*(NND+1)];

    // vpos slice (post-relu, from k_tree) for this lane's d-range
    float vpf[16];
    #pragma unroll
    for (int j = 0; j < 4; ++j){
        float4 x = *(const float4*)&vposG[g*DD + d0 + 4*j];
        vpf[4*j+0]=x.x; vpf[4*j+1]=x.y; vpf[4*j+2]=x.z; vpf[4*j+3]=x.w;
    }
    float4 u0 = *(const float4*)&uG[(size_t)g*NND*DD + 4*k4];

    // ---- step 0: per-e weights W[e] ----
    #pragma unroll 2
    for (int p = 0; p < CH; ++p){
        int e = eBase + p;
        const float* Wp = EW + (size_t)e*(DD*DD) + (size_t)d0*DD + 4*k4;
        float s0=0.f, s1=0.f, s2=0.f, s3=0.f;
        #pragma unroll
        for (int d = 0; d < 16; ++d){
            float4 wv = *(const float4*)&Wp[d*DD];
            s0 = fmaf(vpf[d], wv.x, s0);
            s1 = fmaf(vpf[d], wv.y, s1);
            s2 = fmaf(vpf[d], wv.z, s2);
            s3 = fmaf(vpf[d], wv.w, s3);
        }
        #pragma unroll
        for (int m = 8; m <= 32; m <<= 1){
            s0 += __shfl_xor(s0, m); s1 += __shfl_xor(s1, m);
            s2 += __shfl_xor(s2, m); s3 += __shfl_xor(s3, m);
        }
        if (owner){
            float4 bb = *(const float4*)&EB[(size_t)e*DD + 4*k4];
            float4 r;
            r.x = fmaxf(u0.x + s0 + bb.x, 0.f);
            r.y = fmaxf(u0.y + s1 + bb.y, 0.f);
            r.z = fmaxf(u0.z + s2 + bb.z, 0.f);
            r.w = fmaxf(u0.w + s3 + bb.w, 0.f);
            *(float4*)&Vbuf[0][p][4*k4] = r;
        }
    }
    __syncthreads();

    // ---- shared steps 1..L-1: one W per step, reused across CH e-rows ----
    int cur = 0;
    for (int s = 1; s < L; ++s){
        int pn = meta[g*(NND+1) + s];           // path[s-1]
        int ej = edges[pn];
        const float* Wp = EW + (size_t)ej*(DD*DD) + (size_t)d0*DD + 4*k4;
        float4 wr[16];
        #pragma unroll
        for (int d = 0; d < 16; ++d) wr[d] = *(const float4*)&Wp[d*DD];
        float4 us = *(const float4*)&uG[((size_t)g*NND + s)*DD + 4*k4];
        float4 bb = *(const float4*)&EB[(size_t)ej*DD + 4*k4];
        #pragma unroll
        for (int p = 0; p < CH; ++p){
            float ev[16];
            #pragma unroll
            for (int j = 0; j < 4; ++j){
                float4 x = *(const float4*)&Vbuf[cur][p][d0 + 4*j];
                ev[4*j+0]=x.x; ev[4*j+1]=x.y; ev[4*j+2]=x.z; ev[4*j+3]=x.w;
            }
            float s0=0.f, s1=0.f, s2=0.f, s3=0.f;
            #pragma unroll
            for (int d = 0; d < 16; ++d){
                s0 = fmaf(ev[d], wr[d].x, s0);
                s1 = fmaf(ev[d], wr[d].y, s1);
                s2 = fmaf(ev[d], wr[d].z, s2);
                s3 = fmaf(ev[d], wr[d].w, s3);
            }
            #pragma unroll
            for (int m = 8; m <= 32; m <<= 1){
                s0 += __shfl_xor(s0, m); s1 += __shfl_xor(s1, m);
                s2 += __shfl_xor(s2, m); s3 += __shfl_xor(s3, m);
            }
            if (owner){
                float4 r;
                r.x = fmaxf(us.x + s0 + bb.x, 0.f);
                r.y = fmaxf(us.y + s1 + bb.y, 0.f);
                r.z = fmaxf(us.z + s2 + bb.z, 0.f);
                r.w = fmaxf(us.w + s3 + bb.w, 0.f);
                *(float4*)&Vbuf[cur^1][p][4*k4] = r;
            }
        }
        __syncthreads();
        cur ^= 1;
    }

    // ---- final transform (root edge) + score ----
    {
        int rn = meta[g*(NND+1) + L];           // path[L-1] (= 127)
        int er = edges[rn];
        const float* Wp = EW + (size_t)er*(DD*DD) + (size_t)d0*DD + 4*k4;
        float4 wr[16];
        #pragma unroll
        for (int d = 0; d < 16; ++d) wr[d] = *(const float4*)&Wp[d*DD];
        float4 bb = *(const float4*)&EB[(size_t)er*DD + 4*k4];
        float4 sw = *(const float4*)&SEW[4*k4];
        #pragma unroll
        for (int p = 0; p < CH; ++p){
            float ev[16];
            #pragma unroll
            for (int j = 0; j < 4; ++j){
                float4 x = *(const float4*)&Vbuf[cur][p][d0 + 4*j];
                ev[4*j+0]=x.x; ev[4*j+1]=x.y; ev[4*j+2]=x.z; ev[4*j+3]=x.w;
            }
            float s0=0.f, s1=0.f, s2=0.f, s3=0.f;
            #pragma unroll
            for (int d = 0; d < 16; ++d){
                s0 = fmaf(ev[d], wr[d].x, s0);
                s1 = fmaf(ev[d], wr[d].y, s1);
                s2 = fmaf(ev[d], wr[d].z, s2);
                s3 = fmaf(ev[d], wr[d].w, s3);
            }
            #pragma unroll
            for (int m = 8; m <= 32; m <<= 1){
                s0 += __shfl_xor(s0, m); s1 += __shfl_xor(s1, m);
                s2 += __shfl_xor(s2, m); s3 += __shfl_xor(s3, m);
            }
            if (owner){
                float part = (s0 + bb.x) * sw.x + (s1 + bb.y) * sw.y
                           + (s2 + bb.z) * sw.z + (s3 + bb.w) * sw.w;
                part += __shfl_xor(part, 1);
                part += __shfl_xor(part, 2);
                part += __shfl_xor(part, 4);
                if (l == 0) red[p][w] = part;
            }
        }
        __syncthreads();
        if (t < CH)
            outp[g*DD + eBase + t] = dscore[0] + red[t][0] + red[t][1] + red[t][2] + red[t][3];
    }
}

extern "C" void kernel_launch(void* const* d_in, const int* in_sizes, int n_in,
                              void* d_out, int out_size, void* d_ws, size_t ws_size,
                              hipStream_t stream)
{
    const int*   data   = (const int*)d_in[0];
    /* d_in[1] = types, unused (single data_type) */
    const int*   graphs = (const int*)d_in[2];
    const int*   edges  = (const int*)d_in[3];
    const int*   posArr = (const int*)d_in[4];
    const float* vecs   = (const float*)d_in[5];
    const float* dw     = (const float*)d_in[6];
    const float* db     = (const float*)d_in[7];
    const float* ew     = (const float*)d_in[8];
    const float* eb     = (const float*)d_in[9];
    const float* sew    = (const float*)d_in[10];
    const float* sdw    = (const float*)d_in[11];
    const float* sb     = (const float*)d_in[12];

    char* ws = (char*)d_ws;
    float* base   = (float*)(ws);                               // 64 KB
    float* vposG  = (float*)(ws + 65536);                       // 4 KB
    float* uG     = (float*)(ws + 65536 + 4096);                // 512 KB
    float* dscore = (float*)(ws + 65536 + 4096 + 524288);       // 1 f32
    int*   meta   = (int*)  (ws + 65536 + 4096 + 524288 + 256); // 8*129 ints

    float* outp = (float*)d_out;

    k_base <<<NND, 128, 0, stream>>>(data, posArr, vecs, dw, db, sdw, sb, base, dscore);
    k_tree <<<GG, 1024, 0, stream>>>(graphs, edges, posArr, ew, eb, base, vposG, uG, meta);
    k_chain<<<GG*(DD/CH), 256, 0, stream>>>(edges, ew, eb, sew, vposG, uG, meta, dscore, outp);
}

// Round 2
// 345.811 us; speedup vs baseline: 1.0301x; 1.0301x over previous
//
#include <hip/hip_runtime.h>
#include <stdint.h>

// Net_49177375539428: recursive tree-NN scorer, all-fp32.
//   k_base : base[n,:] = vecs[data[n]] @ Wd + bd ; d_score at n==pos.
//   k_tree : level-parallel (rounds = tree height), 1024 thr / graph.
//            GEMV rewritten: half-wave d-split (lane: 4 cols x 64 d) with
//            explicit ping-pong float4[8] register prefetch -> >=8 W-loads
//            in flight per wave (round-1 had VGPR=48 -> ~3 in flight,
//            latency-bound at 52 GB/s/CU). Target: L1-port ~153 GB/s.
//   k_step0: NEW. One block per edge-type e: W[e] streamed ONCE, reused
//            across all 8 graphs (kills the 8x redundancy of old step 0).
//            Same lane mapping + shfl-tree as old step 0 (bit-identical).
//   k_steps: old k_chain minus step 0. CH=16 (was 4) -> path-W re-streamed
//            8x instead of 32x. Rows independent through the whole chain.

#define NND 128
#define DD  128
#define GG  8
#define VD  300
#define EDGEN 128
#define CH2 16         // e-rows per k_steps block

typedef unsigned int u32;

#define F_POS  (1<<16)
#define F_PATH (1<<17)

// ---------------- K1: base embeddings + d_score ----------------
__global__ void __launch_bounds__(128) k_base(
        const int* __restrict__ data, const int* __restrict__ posArr,
        const float* __restrict__ vecs, const float* __restrict__ dw,
        const float* __restrict__ db,   const float* __restrict__ sdw,
        const float* __restrict__ sb,
        float* __restrict__ base, float* __restrict__ dscore)
{
    __shared__ __align__(16) float row[VD];
    __shared__ float red[DD];
    int n = blockIdx.x, t = threadIdx.x;
    int id = data[n];
    const float4* vp = (const float4*)(vecs + (size_t)id * VD);  // 1200B rows
    for (int i = t; i < VD/4; i += 128) ((float4*)row)[i] = vp[i];
    __syncthreads();
    float a0 = db[t], a1 = 0.f, a2 = 0.f, a3 = 0.f;
    for (int d = 0; d < VD; d += 4){
        a0 = fmaf(row[d+0], dw[(d+0)*DD + t], a0);
        a1 = fmaf(row[d+1], dw[(d+1)*DD + t], a1);
        a2 = fmaf(row[d+2], dw[(d+2)*DD + t], a2);
        a3 = fmaf(row[d+3], dw[(d+3)*DD + t], a3);
    }
    float acc = (a0 + a1) + (a2 + a3);
    base[n*DD + t] = acc;
    if (n == posArr[0]){
        red[t] = acc * sdw[t];
        __syncthreads();
        for (int o = 64; o > 0; o >>= 1){ if (t < o) red[t] += red[t+o]; __syncthreads(); }
        if (t == 0) dscore[0] = sb[0] + red[0];
    }
}

// ---------------- K2: level-parallel tree sweep ----------------
__global__ void __launch_bounds__(1024, 1) k_tree(
        const int* __restrict__ graphs, const int* __restrict__ edges,
        const int* __restrict__ posArr, const float* __restrict__ EW,
        const float* __restrict__ EB,   const float* __restrict__ base,
        float* __restrict__ vposG, float* __restrict__ uG, int* __restrict__ meta)
{
    __shared__ __align__(16) float contrib[NND-1][DD];   // 63.5 KB, nodes 0..126
    __shared__ int par_s[NND], eid_s[NND], flg_s[NND];
    __shared__ int ccnt[NND], cstart[NND], cidx[NND];
    __shared__ int dep[NND], anc[NND], lcnt[NND], lstart[NND], order[NND];
    __shared__ int maxD_s;

    int g = blockIdx.x, t = threadIdx.x;

    // ---- phase 1: load graph structure ----
    if (t < NND){
        par_s[t] = (t < NND-1) ? (t + graphs[g*NND + t]) : (NND-1);  // root self-parent
        eid_s[t] = edges[t];
        flg_s[t] = 0;
        ccnt[t]  = 0;
        lcnt[t]  = 0;
    }
    if (t == 0) maxD_s = 0;
    __syncthreads();

    // ---- phase 2: child counts, sibling slots, depth init, path walk ----
    int mySlot = 0;
    if (t < NND-1){
        int p = par_s[t];
        atomicAdd(&ccnt[p], 1);
        for (int c = 0; c < t; ++c) mySlot += (par_s[c] == p);  // ascending sibling order
    }
    if (t < NND){
        dep[t] = (t < NND-1) ? 1 : 0;
        anc[t] = par_s[t];
    }
    if (t == 0){
        int p = posArr[0];
        flg_s[p] |= F_POS;
        int c = par_s[p], s = 0;
        for (;;){
            flg_s[c] |= F_PATH | (s << 24);
            meta[g*(NND+1) + 1 + s] = c;
            ++s;
            if (c == NND-1) break;
            c = par_s[c];
        }
        meta[g*(NND+1)] = s;                        // path length L
    }
    __syncthreads();

    // ---- phase 3: child list offsets ----
    if (t < NND){
        int s = 0;
        for (int p = 0; p < t; ++p) s += ccnt[p];
        cstart[t] = s;
    }
    __syncthreads();
    if (t < NND-1) cidx[cstart[par_s[t]] + mySlot] = t;

    // ---- phase 4: depth via pointer jumping ----
    for (int k = 0; k < 7; ++k){
        int d2 = 0, a2 = 0;
        if (t < NND){ d2 = dep[t] + dep[anc[t]]; a2 = anc[anc[t]]; }
        __syncthreads();
        if (t < NND){ dep[t] = d2; anc[t] = a2; }
        __syncthreads();
    }
    if (t < NND) atomicMax(&maxD_s, dep[t]);
    if (t < NND) atomicAdd(&lcnt[dep[t]], 1);
    __syncthreads();

    // ---- phase 5: bucket nodes by depth ----
    if (t < NND){
        int s = 0;
        for (int d2 = 0; d2 < t; ++d2) s += lcnt[d2];
        lstart[t] = s;
    }
    __syncthreads();
    if (t < NND){
        int d2 = dep[t], s = 0;
        for (int c = 0; c < t; ++c) s += (dep[c] == d2);
        order[lstart[d2] + s] = t;
    }
    __syncthreads();

    // ---- main: rounds from deepest depth up to root ----
    int w = t >> 6, l = t & 63;
    int c0 = 2*l;                       // gather mapping: 2 cols/lane
    int li = l & 31, hl = l >> 5;       // GEMV mapping: 4 cols x half-d
    int c4 = 4*li, dbase = 64*hl;
    int maxD = maxD_s;

    for (int d = maxD; d >= 0; --d){
        int lo = lstart[d], cnt = lcnt[d];
        for (int q = w; q < cnt; q += 16){
            int n = order[lo + q];                  // wave-uniform
            float2 bse = *(const float2*)&base[n*DD + c0];
            float e0 = bse.x, e1 = bse.y;
            int cs = cstart[n], cc = ccnt[n];
            for (int j = 0; j < cc; ++j){
                int c = cidx[cs + j];
                if (!(flg_s[c] & (F_POS | F_PATH))){
                    float2 cv = *(const float2*)&contrib[c][c0];
                    e0 += cv.x; e1 += cv.y;
                }
            }
            int f = flg_s[n];
            if (f & F_POS){
                if (cc){ e0 = fmaxf(e0, 0.f); e1 = fmaxf(e1, 0.f); }
                *(float2*)&vposG[g*DD + c0] = make_float2(e0, e1);
            } else if (f & F_PATH){
                int slot = ((u32)f) >> 24;
                *(float2*)&uG[((size_t)g*NND + slot)*DD + c0] = make_float2(e0, e1);  // pre-relu
            } else {
                if (cc){ e0 = fmaxf(e0, 0.f); e1 = fmaxf(e1, 0.f); }
                *(float2*)&contrib[n][c0] = make_float2(e0, e1);       // stage emb
                asm volatile("s_waitcnt lgkmcnt(0)" ::: "memory");     // wave-internal LDS RAW
                int e = eid_s[n];
                const float* Wp = EW + (size_t)e*(DD*DD) + (size_t)dbase*DD + c4;
                const float* xr = &contrib[n][dbase];
                float4 A[8], B[8];
                float s0=0.f, s1=0.f, s2=0.f, s3=0.f;
                #define LW(buf, gi) { _Pragma("unroll") \
                    for (int j2 = 0; j2 < 8; ++j2) \
                        buf[j2] = *(const float4*)&Wp[(size_t)((gi)*8 + j2)*DD]; }
                #define CP(buf, gi) { _Pragma("unroll") \
                    for (int j2 = 0; j2 < 8; ++j2){ \
                        float x = xr[(gi)*8 + j2]; \
                        s0 = fmaf(x, buf[j2].x, s0); s1 = fmaf(x, buf[j2].y, s1); \
                        s2 = fmaf(x, buf[j2].z, s2); s3 = fmaf(x, buf[j2].w, s3); } }
                LW(A,0); LW(B,1);
                CP(A,0); LW(A,2);
                CP(B,1); LW(B,3);
                CP(A,2); LW(A,4);
                CP(B,3); LW(B,5);
                CP(A,4); LW(A,6);
                CP(B,5); LW(B,7);
                CP(A,6);
                CP(B,7);
                #undef LW
                #undef CP
                s0 += __shfl_xor(s0, 32);          // low-half sum + high-half sum
                s1 += __shfl_xor(s1, 32);
                s2 += __shfl_xor(s2, 32);
                s3 += __shfl_xor(s3, 32);
                if (hl == 0){
                    float4 bb = *(const float4*)&EB[(size_t)e*DD + c4];
                    *(float4*)&contrib[n][c4] =
                        make_float4(s0 + bb.x, s1 + bb.y, s2 + bb.z, s3 + bb.w);
                }
            }
        }
        __syncthreads();
    }
}

// ---------------- K3a: step 0, batched over graphs ----------------
// One block per edge-type e. W[e] loaded once into registers, reused for
// all 8 graphs. Lane mapping + shfl tree identical to the old step 0.
__global__ void __launch_bounds__(256, 1) k_step0(
        const float* __restrict__ EW, const float* __restrict__ EB,
        const float* __restrict__ vposG, const float* __restrict__ uG,
        float* __restrict__ V0)
{
    __shared__ __align__(16) float vpos_s[GG][DD];
    int e = blockIdx.x, t = threadIdx.x, l = t & 63, w = t >> 6;
    {
        int idx = t;                                 // GG*DD/4 == 256 exactly
        ((float4*)vpos_s)[idx] = ((const float4*)vposG)[idx];
    }
    __syncthreads();
    int k4 = w*8 + (l & 7);
    int d0 = (l >> 3) * 16;
    bool owner = ((l >> 3) == 0);
    const float* Wp = EW + (size_t)e*(DD*DD) + (size_t)d0*DD + 4*k4;
    float4 wr[16];
    #pragma unroll
    for (int d = 0; d < 16; ++d) wr[d] = *(const float4*)&Wp[d*DD];
    float4 bb = *(const float4*)&EB[(size_t)e*DD + 4*k4];
    for (int g = 0; g < GG; ++g){
        float s0=0.f, s1=0.f, s2=0.f, s3=0.f;
        #pragma unroll
        for (int d = 0; d < 16; ++d){
            float x = vpos_s[g][d0 + d];
            s0 = fmaf(x, wr[d].x, s0);
            s1 = fmaf(x, wr[d].y, s1);
            s2 = fmaf(x, wr[d].z, s2);
            s3 = fmaf(x, wr[d].w, s3);
        }
        #pragma unroll
        for (int m = 8; m <= 32; m <<= 1){
            s0 += __shfl_xor(s0, m); s1 += __shfl_xor(s1, m);
            s2 += __shfl_xor(s2, m); s3 += __shfl_xor(s3, m);
        }
        if (owner){
            float4 u0 = *(const float4*)&uG[(size_t)g*NND*DD + 4*k4];
            float4 r;
            r.x = fmaxf(u0.x + s0 + bb.x, 0.f);
            r.y = fmaxf(u0.y + s1 + bb.y, 0.f);
            r.z = fmaxf(u0.z + s2 + bb.z, 0.f);
            r.w = fmaxf(u0.w + s3 + bb.w, 0.f);
            *(float4*)&V0[((size_t)g*EDGEN + e)*DD + 4*k4] = r;
        }
    }
}

// ---------------- K3b: path chains, 16 e-rows per block ----------------
__global__ void __launch_bounds__(256, 1) k_steps(
        const int* __restrict__ edges,
        const float* __restrict__ EW, const float* __restrict__ EB,
        const float* __restrict__ SEW,
        const float* __restrict__ uG, const float* __restrict__ V0,
        const int* __restrict__ meta, const float* __restrict__ dscore,
        float* __restrict__ outp)
{
    __shared__ __align__(16) float Vbuf[2][CH2][DD];
    __shared__ float red[CH2][4];
    int g = blockIdx.x >> 3, chunk = blockIdx.x & 7;
    int t = threadIdx.x, l = t & 63, w = t >> 6;
    int k4 = w*8 + (l & 7);
    int d0 = (l >> 3) * 16;
    bool owner = ((l >> 3) == 0);
    int eBase = chunk * CH2;
    int L = meta[g*(NND+1)];

    // load this block's 16 step-0 rows
    for (int idx = t; idx < CH2*DD/4; idx += 256)
        ((float4*)&Vbuf[0][0][0])[idx] =
            ((const float4*)&V0[((size_t)g*EDGEN + eBase)*DD])[idx];
    __syncthreads();

    // ---- shared steps 1..L-1: one W per step, reused across CH2 e-rows ----
    int cur = 0;
    for (int s = 1; s < L; ++s){
        int pn = meta[g*(NND+1) + s];           // path[s-1]
        int ej = edges[pn];
        const float* Wp = EW + (size_t)ej*(DD*DD) + (size_t)d0*DD + 4*k4;
        float4 wr[16];
        #pragma unroll
        for (int d = 0; d < 16; ++d) wr[d] = *(const float4*)&Wp[d*DD];
        float4 us = *(const float4*)&uG[((size_t)g*NND + s)*DD + 4*k4];
        float4 bb = *(const float4*)&EB[(size_t)ej*DD + 4*k4];
        #pragma unroll 4
        for (int p = 0; p < CH2; ++p){
            float ev[16];
            #pragma unroll
            for (int j = 0; j < 4; ++j){
                float4 x = *(const float4*)&Vbuf[cur][p][d0 + 4*j];
                ev[4*j+0]=x.x; ev[4*j+1]=x.y; ev[4*j+2]=x.z; ev[4*j+3]=x.w;
            }
            float s0=0.f, s1=0.f, s2=0.f, s3=0.f;
            #pragma unroll
            for (int d = 0; d < 16; ++d){
                s0 = fmaf(ev[d], wr[d].x, s0);
                s1 = fmaf(ev[d], wr[d].y, s1);
                s2 = fmaf(ev[d], wr[d].z, s2);
                s3 = fmaf(ev[d], wr[d].w, s3);
            }
            #pragma unroll
            for (int m = 8; m <= 32; m <<= 1){
                s0 += __shfl_xor(s0, m); s1 += __shfl_xor(s1, m);
                s2 += __shfl_xor(s2, m); s3 += __shfl_xor(s3, m);
            }
            if (owner){
                float4 r;
                r.x = fmaxf(us.x + s0 + bb.x, 0.f);
                r.y = fmaxf(us.y + s1 + bb.y, 0.f);
                r.z = fmaxf(us.z + s2 + bb.z, 0.f);
                r.w = fmaxf(us.w + s3 + bb.w, 0.f);
                *(float4*)&Vbuf[cur^1][p][4*k4] = r;
            }
        }
        __syncthreads();
        cur ^= 1;
    }

    // ---- final transform (root edge) + score ----
    {
        int rn = meta[g*(NND+1) + L];           // path[L-1] (= 127)
        int er = edges[rn];
        const float* Wp = EW + (size_t)er*(DD*DD) + (size_t)d0*DD + 4*k4;
        float4 wr[16];
        #pragma unroll
        for (int d = 0; d < 16; ++d) wr[d] = *(const float4*)&Wp[d*DD];
        float4 bb = *(const float4*)&EB[(size_t)er*DD + 4*k4];
        float4 sw = *(const float4*)&SEW[4*k4];
        #pragma unroll 4
        for (int p = 0; p < CH2; ++p){
            float ev[16];
            #pragma unroll
            for (int j = 0; j < 4; ++j){
                float4 x = *(const float4*)&Vbuf[cur][p][d0 + 4*j];
                ev[4*j+0]=x.x; ev[4*j+1]=x.y; ev[4*j+2]=x.z; ev[4*j+3]=x.w;
            }
            float s0=0.f, s1=0.f, s2=0.f, s3=0.f;
            #pragma unroll
            for (int d = 0; d < 16; ++d){
                s0 = fmaf(ev[d], wr[d].x, s0);
                s1 = fmaf(ev[d], wr[d].y, s1);
                s2 = fmaf(ev[d], wr[d].z, s2);
                s3 = fmaf(ev[d], wr[d].w, s3);
            }
            #pragma unroll
            for (int m = 8; m <= 32; m <<= 1){
                s0 += __shfl_xor(s0, m); s1 += __shfl_xor(s1, m);
                s2 += __shfl_xor(s2, m); s3 += __shfl_xor(s3, m);
            }
            if (owner){
                float part = (s0 + bb.x) * sw.x + (s1 + bb.y) * sw.y
                           + (s2 + bb.z) * sw.z + (s3 + bb.w) * sw.w;
                part += __shfl_xor(part, 1);
                part += __shfl_xor(part, 2);
                part += __shfl_xor(part, 4);
                if (l == 0) red[p][w] = part;
            }
        }
        __syncthreads();
        if (t < CH2)
            outp[g*DD + eBase + t] = dscore[0] + red[t][0] + red[t][1] + red[t][2] + red[t][3];
    }
}

extern "C" void kernel_launch(void* const* d_in, const int* in_sizes, int n_in,
                              void* d_out, int out_size, void* d_ws, size_t ws_size,
                              hipStream_t stream)
{
    const int*   data   = (const int*)d_in[0];
    /* d_in[1] = types, unused (single data_type) */
    const int*   graphs = (const int*)d_in[2];
    const int*   edges  = (const int*)d_in[3];
    const int*   posArr = (const int*)d_in[4];
    const float* vecs   = (const float*)d_in[5];
    const float* dw     = (const float*)d_in[6];
    const float* db     = (const float*)d_in[7];
    const float* ew     = (const float*)d_in[8];
    const float* eb     = (const float*)d_in[9];
    const float* sew    = (const float*)d_in[10];
    const float* sdw    = (const float*)d_in[11];
    const float* sb     = (const float*)d_in[12];

    char* ws = (char*)d_ws;
    float* base   = (float*)(ws);                               // 64 KB
    float* vposG  = (float*)(ws + 65536);                       // 4 KB
    float* uG     = (float*)(ws + 65536 + 4096);                // 512 KB
    float* dscore = (float*)(ws + 593920);                      // 1 f32 (256 B pad)
    int*   meta   = (int*)  (ws + 594176);                      // 8*129 ints
    float* V0     = (float*)(ws + 598528);                      // 512 KB

    float* outp = (float*)d_out;

    k_base <<<NND, 128, 0, stream>>>(data, posArr, vecs, dw, db, sdw, sb, base, dscore);
    k_tree <<<GG, 1024, 0, stream>>>(graphs, edges, posArr, ew, eb, base, vposG, uG, meta);
    k_step0<<<EDGEN, 256, 0, stream>>>(ew, eb, vposG, uG, V0);
    k_steps<<<GG*(EDGEN/CH2), 256, 0, stream>>>(edges, ew, eb, sew, uG, V0, meta, dscore, outp);
}